// Round 8
// baseline (331.683 us; speedup 1.0000x reference)
//
#include <hip/hip_runtime.h>
#include <math.h>

#define TT 8192
#define BB 256
#define EE 8
#define KK 15
#define PI_F  3.14159265358979323846f
#define TPI_F 6.28318530717958647692f

// d_out flat layout (reference tuple order)
#define OFF_OUT 0
#define OFF_LAT (BB*TT)
#define OFF_SIG (OFF_LAT + BB*EE*TT)
#define OFF_P   (OFF_SIG + BB*EE*TT)
#define OFF_F   (OFF_P + BB*EE)
#define OFF_A   (OFF_F + BB*EE)
#define OFF_B0  (OFF_A + BB*EE)

// swizzle for fft LDS only
#define SWZ(i) ((i) + ((i) >> 5))
#define NF 4096

// fused-kernel LDS layout (floats). re/im: SWZ(4095)+1 = 4223 each.
// NO sxp staging (R8): x row is 32KB, cache-resident -> conv reads
// windows straight from global. LDS 8574 fl = 34296 B -> 4 blocks/CU.
#define L_RE   0
#define L_IM   4223
#define L_SW   8446        // 96 floats
#define L_RBUF 8542        // 32 floats
#define L_TOT  8574

__device__ __forceinline__ float rdfl(float v) {
  return __uint_as_float(__builtin_amdgcn_readfirstlane(__float_as_uint(v)));
}

__device__ __forceinline__ int rev4(int k) {   // base-4 digit reversal, 6 digits
  unsigned r = __brev((unsigned)k) >> 20;      // 12-bit bit reversal
  return (int)(((r & 0x555u) << 1) | ((r >> 1) & 0x555u));
}

// =====================================================================
// FUSED Kernel A+B: composed dilated conv -> real-packed FFT -> moments
// + fc phase, one block per (e, b). 2048 blocks x 512 threads.
//
// R8: conv windows read DIRECTLY from global x (no sxp LDS staging).
//  - win[s] = x[(m0+s-14)*d + ph], zeros outside [0,TT) -- identical
//    values to the old staged path, so edge-correction code is unchanged
//    (conditions now on global m0: first m0<=6, last m0+r+j >= M+7).
//  - interior threads (m0 in [16, M-20]) take an unguarded load path;
//    lanes span ph -> coalesced for e>=6, L1/L2-served below.
//  - LDS halves (66->34 KB) -> 4 blocks/CU; staging loop + 2 barriers
//    deleted. Phase-diverse block overlap is the point of the fusion.
// =====================================================================
__global__ __launch_bounds__(512) void conv_fft_kernel(
    const float* __restrict__ x, const float* __restrict__ W1,
    const float* __restrict__ b1, const float* __restrict__ W2,
    const float* __restrict__ b2, const float* __restrict__ fcW,
    const float* __restrict__ fcb, float* __restrict__ latent,
    float* __restrict__ outP, float* __restrict__ outF,
    float* __restrict__ outA, float* __restrict__ outB0)
{
  extern __shared__ float smem[];
  float* re   = smem + L_RE;
  float* im   = smem + L_IM;
  float* sW   = smem + L_SW;
  float* rbuf = smem + L_RBUF;

  const int e = blockIdx.x, b = blockIdx.y;
  const int d  = 1 << e;
  const int M  = TT >> e;                   // outputs per phase (full row)
  const int tid = threadIdx.x;
  const float* xr = x + b * TT;

  // ---- weights: composed 29-tap + raw
  if (tid < 29) {
    float acc = 0.0f;
    for (int c = 0; c < 2; c++) {
      const float* w1 = W1 + e*30 + c*15;
      const float* w2 = W2 + e*30 + c*15;
      int jlo = tid - 14; if (jlo < 0) jlo = 0;
      int jhi = tid;      if (jhi > 14) jhi = 14;
      for (int j = jlo; j <= jhi; j++) acc += w2[j] * w1[tid - j];
    }
    sW[tid] = acc;
  } else if (tid == 29) {
    float s20 = 0.f, s21 = 0.f;
    for (int j = 0; j < 15; j++) { s20 += W2[e*30 + j]; s21 += W2[e*30 + 15 + j]; }
    sW[29] = b2[e] + s20*b1[e*2] + s21*b1[e*2 + 1];
  } else if (tid >= 32 && tid < 62) {
    sW[tid] = W1[e*30 + (tid - 32)];
  } else if (tid >= 64 && tid < 94) {
    sW[tid] = W2[e*30 + (tid - 64)];
  } else if (tid == 94 || tid == 95) {
    sW[tid] = b1[e*2 + (tid - 94)];
  }
  __syncthreads();

  float Wc[29];
  #pragma unroll
  for (int s = 0; s < 29; s++) Wc[s] = rdfl(sW[s]);
  const float Bc = rdfl(sW[29]);

  float* lr = latent + (b * EE + e) * TT;

  // ---- conv: 4 groups of 4 chain outputs per thread (2048 vthreads)
  #pragma unroll 1
  for (int g = 0; g < 4; g++) {
    const int vt = g * 512 + tid;            // 0..2047
    const int ph = vt & (d - 1);
    const int m0 = (vt >> e) << 2;           // phase-local first output idx
    const float* xp = xr + ph;
    const int nbase = m0 - 14;

    float win[32];
    if (m0 >= 16 && m0 <= M - 20) {
      #pragma unroll
      for (int s = 0; s < 32; s++) win[s] = xp[(nbase + s) * d];
    } else {
      #pragma unroll
      for (int s = 0; s < 32; s++) {
        int ns = nbase + s;
        win[s] = ((unsigned)ns < (unsigned)M) ? xp[ns * d] : 0.0f;
      }
    }

    float acc[4] = {Bc, Bc, Bc, Bc};
    #pragma unroll
    for (int s = 0; s < 29; s++) {
      #pragma unroll
      for (int r = 0; r < 4; r++) acc[r] = fmaf(Wc[s], win[s + r], acc[r]);
    }

    // ---- first-edge correction (global row start)
    if (m0 <= 6) {
      #pragma unroll
      for (int r = 0; r < 4; r++) {
        float corr = 0.0f;
        #pragma unroll
        for (int j = 0; j < 7; j++) {
          if (m0 + r + j <= 6) {
            float a0 = sW[94], a1 = sW[95];
            #pragma unroll
            for (int k = 0; k < 15; k++) {
              float xv = win[r + j + k];
              a0 = fmaf(sW[32 + k], xv, a0);
              a1 = fmaf(sW[47 + k], xv, a1);
            }
            corr = fmaf(sW[64 + j], a0, corr);
            corr = fmaf(sW[79 + j], a1, corr);
          }
        }
        acc[r] -= corr;
      }
    }
    // ---- last-edge correction (global row end)
    if (m0 + 3 >= M - 7) {
      #pragma unroll
      for (int r = 0; r < 4; r++) {
        float corr = 0.0f;
        #pragma unroll
        for (int jj = 0; jj < 7; jj++) {
          const int j = 8 + jj;
          if (m0 + r + j >= M + 7) {
            float a0 = sW[94], a1 = sW[95];
            #pragma unroll
            for (int k = 0; k < 15; k++) {
              float xv = win[r + j + k];
              a0 = fmaf(sW[32 + k], xv, a0);
              a1 = fmaf(sW[47 + k], xv, a1);
            }
            corr = fmaf(sW[64 + j], a0, corr);
            corr = fmaf(sW[79 + j], a1, corr);
          }
        }
        acc[r] -= corr;
      }
    }

    // ---- store to global latent + scatter real-packed into re/im LDS
    #pragma unroll
    for (int r = 0; r < 4; r++) {
      int tg = ph + (m0 + r) * d;
      lr[tg] = acc[r];
      int n  = tg >> 1;
      float* dst = (tg & 1) ? im : re;
      dst[SWZ(n)] = acc[r];
    }
  }
  __syncthreads();

  // ---- fc dot-product pass
  const float2* f02 = (const float2*)(fcW + (e*2 + 0)*TT);
  const float2* f12 = (const float2*)(fcW + (e*2 + 1)*TT);
  float v0 = 0.f, v1 = 0.f;
  for (int n = tid; n < NF; n += 512) {
    float zr = re[SWZ(n)], zi = im[SWZ(n)];
    float2 a0 = f02[n], a1 = f12[n];
    v0 = fmaf(zr, a0.x, v0); v0 = fmaf(zi, a0.y, v0);
    v1 = fmaf(zr, a1.x, v1); v1 = fmaf(zi, a1.y, v1);
  }
  __syncthreads();

  // ---- radix-4 DIF stages
  for (int L = NF >> 2; L >= 1; L >>= 2) {
    float wstep = -1.57079632679f / (float)L;
    for (int u = tid; u < (NF >> 2); u += 512) {
      int p = u & (L - 1);
      int base = ((u - p) << 2) + p;
      int i0 = SWZ(base), i1 = SWZ(base + L), i2 = SWZ(base + 2*L), i3 = SWZ(base + 3*L);
      float ar = re[i0], ai = im[i0];
      float br = re[i1], bi = im[i1];
      float cr = re[i2], ci = im[i2];
      float dr = re[i3], di = im[i3];
      float t0r = ar + cr, t0i = ai + ci;
      float t1r = ar - cr, t1i = ai - ci;
      float t2r = br + dr, t2i = bi + di;
      float t3r = br - dr, t3i = bi - di;
      float A0r = t0r + t2r, A0i = t0i + t2i;
      float A1r = t1r + t3i, A1i = t1i - t3r;
      float A2r = t0r - t2r, A2i = t0i - t2i;
      float A3r = t1r - t3i, A3i = t1i + t3r;
      float ang = wstep * (float)p;
      float s1 = __sinf(ang), c1 = __cosf(ang);
      float c2 = c1*c1 - s1*s1, s2 = 2.f*c1*s1;
      float c3 = c1*c2 - s1*s2, s3 = c1*s2 + s1*c2;
      re[i0] = A0r;                 im[i0] = A0i;
      re[i1] = A1r*c1 - A1i*s1;     im[i1] = A1r*s1 + A1i*c1;
      re[i2] = A2r*c2 - A2i*s2;     im[i2] = A2r*s2 + A2i*c2;
      re[i3] = A3r*c3 - A3i*s3;     im[i3] = A3r*s3 + A3i*c3;
    }
    __syncthreads();
  }

  // ---- moments over unpacked real spectrum
  float pacc = 0.f, facc = 0.f;
  for (int k = 1 + tid; k < NF; k += 512) {
    int jk = SWZ(rev4(k));
    int jm = SWZ(rev4(NF - k));
    float zr = re[jk], zi = im[jk];
    float yr = re[jm], yi = im[jm];
    float Er = 0.5f*(zr + yr), Ei = 0.5f*(zi - yi);
    float Dr = 0.5f*(zr - yr), Di = 0.5f*(zi + yi);
    float Or = Di, Oi = -Dr;
    float ang = -PI_F * (float)k / (float)NF;
    float s = __sinf(ang), c = __cosf(ang);
    float Xr = Er + c*Or - s*Oi;
    float Xi = Ei + c*Oi + s*Or;
    float mag = fmaf(Xr, Xr, Xi*Xi);
    pacc += mag;
    facc = fmaf(0.5f * (float)k, mag, facc);
  }
  if (tid == 0) {
    float X = re[SWZ(0)] - im[SWZ(0)];
    pacc += X*X;
    facc += 2048.0f * X*X;
  }

  #pragma unroll
  for (int off = 32; off > 0; off >>= 1) {
    pacc += __shfl_down(pacc, off);
    facc += __shfl_down(facc, off);
    v0   += __shfl_down(v0, off);
    v1   += __shfl_down(v1, off);
  }
  int wid = tid >> 6, lane = tid & 63;
  if (lane == 0) {
    rbuf[wid*4 + 0] = pacc; rbuf[wid*4 + 1] = facc;
    rbuf[wid*4 + 2] = v0;   rbuf[wid*4 + 3] = v1;
  }
  __syncthreads();
  if (tid == 0) {
    float P = 0.f, Fw = 0.f, V0 = 0.f, V1 = 0.f;
    #pragma unroll
    for (int w = 0; w < 8; w++) {
      P += rbuf[w*4]; Fw += rbuf[w*4+1]; V0 += rbuf[w*4+2]; V1 += rbuf[w*4+3];
    }
    float z0r = re[SWZ(0)], z0i = im[SWZ(0)];
    float amp  = 2.0f * sqrtf(P) / (float)TT;
    float boff = (z0r + z0i) / (float)TT;
    float vv0 = V0 + fcb[e*2 + 0];
    float vv1 = V1 + fcb[e*2 + 1];
    float ph  = atan2f(vv1, vv0) / TPI_F;
    int idx = b*EE + e;
    outP[idx]  = ph;
    outF[idx]  = Fw / P;
    outA[idx]  = amp;
    outB0[idx] = boff;
  }
}

// =====================================================================
// Kernel C: sinusoid reconstruction + deconv tree, FULLY CLOSED-FORM.
// (UNCHANGED from R7 -- passed, ~write-bound floor.)
// =====================================================================
#define TILE_C 512
// patch LDS offsets (floats)
#define P_S   128           // 8 x 42
#define P_A   472           // 4 x 35
#define P_B   616           // 2 x 28
#define P_TOT 704

__global__ __launch_bounds__(256) void sig_deconv_kernel(
    const float* __restrict__ Pv, const float* __restrict__ Fv,
    const float* __restrict__ Av, const float* __restrict__ B0v,
    const float* __restrict__ dW0, const float* __restrict__ db0,
    const float* __restrict__ dW1, const float* __restrict__ db1,
    const float* __restrict__ dW2, const float* __restrict__ db2,
    float* __restrict__ sig, float* __restrict__ out)
{
  __shared__ float smem[P_TOT];

  const int tile = blockIdx.x, b = blockIdx.y;
  const int t0 = tile * TILE_C;
  const int tid = threadIdx.x;
  const float step = 2.0f / 8191.0f;

  float fs[8], am[8], psh[8], bo[8];
  #pragma unroll
  for (int ch = 0; ch < EE; ch++) {
    int idx = b*EE + ch;
    fs[ch] = Fv[idx]; am[ch] = Av[idx]; psh[ch] = Pv[idx]; bo[ch] = B0v[idx];
  }

  float* hre   = smem;          // [lvl*8 + ch]
  float* him   = smem + 24;
  float* ssum  = smem + 48;
  float* Cs    = smem + 72;     // am*Re(Htot)
  float* Cc    = smem + 80;     // am*Im(Htot)
  float* chDC  = smem + 88;
  float* bDC   = smem + 96;

  if (tid < 24) {
    int ch  = tid & 7;
    int lvl = tid >> 3;
    const float* w;
    if (lvl == 0)      w = dW0 + (ch >> 1)*30 + (ch & 1)*15;
    else if (lvl == 1) w = dW1 + (ch >> 2)*30 + ((ch >> 1) & 1)*15;
    else               w = dW2 + (ch >> 2)*15;
    float om = TPI_F * fs[ch] * step;       // per-sample angular freq
    float ar = 0.f, ai = 0.f, sm = 0.f;
    #pragma unroll
    for (int k = 0; k < 15; k++) {
      float wk = w[k];
      float ang = (float)(k - 7) * om;
      ar = fmaf(wk, __cosf(ang), ar);
      ai = fmaf(wk, __sinf(ang), ai);
      sm += wk;
    }
    hre[tid] = ar; him[tid] = ai; ssum[tid] = sm;
  }
  __syncthreads();

  if (tid < 8) {
    int ch = tid;
    float r0 = hre[ch],      i0 = him[ch];
    float r1 = hre[8 + ch],  i1 = him[8 + ch];
    float r2 = hre[16 + ch], i2 = him[16 + ch];
    float ra = r0*r1 - i0*i1, ia = r0*i1 + i0*r1;
    float rt = ra*r2 - ia*i2, it = ra*i2 + ia*r2;
    Cs[ch] = am[ch] * rt;
    Cc[ch] = am[ch] * it;
    chDC[ch] = bo[ch] * ssum[ch] * ssum[8 + ch] * ssum[16 + ch];
  } else if (tid == 8) {
    float acc = db2[0];
    #pragma unroll
    for (int g0 = 0; g0 < 4; g0++)
      acc = fmaf(db0[g0], ssum[8 + 2*g0] * ssum[16 + 2*g0], acc);
    #pragma unroll
    for (int g1 = 0; g1 < 2; g1++)
      acc = fmaf(db1[g1], ssum[16 + 4*g1], acc);
    bDC[0] = acc;
  }
  __syncthreads();

  float cs[8], cc[8];
  float DC = bDC[0];
  #pragma unroll
  for (int ch = 0; ch < 8; ch++) {
    cs[ch] = Cs[ch]; cc[ch] = Cc[ch]; DC += chDC[ch];
  }

  const int tmin = (tile == 0)  ? 21        : 0;
  const int tmax = (tile == 15) ? (TT - 21) : TT;
  float* orow = out + b*TT;
  #pragma unroll
  for (int it = 0; it < 2; ++it) {
    int t = t0 + it*256 + tid;
    float arg = fmaf(step, (float)t, -1.0f);
    float o = DC;
    #pragma unroll
    for (int ch = 0; ch < 8; ch++) {
      float rr = fmaf(fs[ch], arg, psh[ch]);
      rr -= rintf(rr);
      float th = TPI_F * rr;
      float s = __sinf(th);
      float c = __cosf(th);
      sig[(b*EE + ch)*TT + t] = fmaf(am[ch], s, bo[ch]);
      o = fmaf(s, cs[ch], o);
      o = fmaf(c, cc[ch], o);
    }
    if (t >= tmin && t < tmax) orow[t] = o;
  }

  // ---- exact border patches (clipped support); head in tile 0, tail in 15
  if (tile == 0) {
    float* Sp = smem + P_S;   // [ch*42 + j], t = j
    float* Ap = smem + P_A;   // [g*35 + j],  v = j
    float* Bp = smem + P_B;   // [g1*28 + j], u = j
    __syncthreads();
    for (int idx = tid; idx < 336; idx += 256) {
      int ch = idx / 42, j = idx - ch*42;
      float arg = fmaf(step, (float)j, -1.0f);
      float rr = fmaf(fs[ch], arg, psh[ch]);
      rr -= rintf(rr);
      Sp[idx] = fmaf(am[ch], __sinf(TPI_F * rr), bo[ch]);
    }
    __syncthreads();
    if (tid < 140) {
      int g = tid / 35, j = tid - g*35;
      float a = db0[g];
      #pragma unroll
      for (int k = 0; k < 15; k++) {
        int is = j + k - 7;
        float s0 = (is >= 0) ? Sp[(2*g)*42 + is]     : 0.0f;
        float s1 = (is >= 0) ? Sp[(2*g+1)*42 + is]   : 0.0f;
        a = fmaf(dW0[g*30 + k],      s0, a);
        a = fmaf(dW0[g*30 + 15 + k], s1, a);
      }
      Ap[tid] = a;
    }
    __syncthreads();
    if (tid < 56) {
      int g1 = tid / 28, j = tid - g1*28;
      float a = db1[g1];
      #pragma unroll
      for (int k = 0; k < 15; k++) {
        int ia = j + k - 7;
        float a0 = (ia >= 0) ? Ap[(2*g1)*35 + ia]   : 0.0f;
        float a1 = (ia >= 0) ? Ap[(2*g1+1)*35 + ia] : 0.0f;
        a = fmaf(dW1[g1*30 + k],      a0, a);
        a = fmaf(dW1[g1*30 + 15 + k], a1, a);
      }
      Bp[tid] = a;
    }
    __syncthreads();
    if (tid < 21) {
      float a = db2[0];
      #pragma unroll
      for (int k = 0; k < 15; k++) {
        int ib = tid + k - 7;
        float b0v_ = (ib >= 0) ? Bp[ib]      : 0.0f;
        float b1v_ = (ib >= 0) ? Bp[28 + ib] : 0.0f;
        a = fmaf(dW2[k],      b0v_, a);
        a = fmaf(dW2[15 + k], b1v_, a);
      }
      orow[tid] = a;
    }
  }
  if (tile == 15) {
    float* Sp = smem + P_S;   // [ch*42 + j], t = 8150 + j
    float* Ap = smem + P_A;   // [g*35 + j],  v = 8157 + j
    float* Bp = smem + P_B;   // [g1*28 + j], u = 8164 + j
    __syncthreads();
    for (int idx = tid; idx < 336; idx += 256) {
      int ch = idx / 42, j = idx - ch*42;
      int t = 8150 + j;
      float arg = fmaf(step, (float)t, -1.0f);
      float rr = fmaf(fs[ch], arg, psh[ch]);
      rr -= rintf(rr);
      Sp[idx] = fmaf(am[ch], __sinf(TPI_F * rr), bo[ch]);
    }
    __syncthreads();
    if (tid < 140) {
      int g = tid / 35, j = tid - g*35;
      float a = db0[g];
      #pragma unroll
      for (int k = 0; k < 15; k++) {
        int is = j + k;                     // local S idx; global = v+k-7
        float s0 = (is < 42) ? Sp[(2*g)*42 + is]   : 0.0f;
        float s1 = (is < 42) ? Sp[(2*g+1)*42 + is] : 0.0f;
        a = fmaf(dW0[g*30 + k],      s0, a);
        a = fmaf(dW0[g*30 + 15 + k], s1, a);
      }
      Ap[tid] = a;
    }
    __syncthreads();
    if (tid < 56) {
      int g1 = tid / 28, j = tid - g1*28;
      float a = db1[g1];
      #pragma unroll
      for (int k = 0; k < 15; k++) {
        int ia = j + k;
        float a0 = (ia < 35) ? Ap[(2*g1)*35 + ia]   : 0.0f;
        float a1 = (ia < 35) ? Ap[(2*g1+1)*35 + ia] : 0.0f;
        a = fmaf(dW1[g1*30 + k],      a0, a);
        a = fmaf(dW1[g1*30 + 15 + k], a1, a);
      }
      Bp[tid] = a;
    }
    __syncthreads();
    if (tid < 21) {
      float a = db2[0];
      #pragma unroll
      for (int k = 0; k < 15; k++) {
        int ib = tid + k;
        float b0v_ = (ib < 28) ? Bp[ib]      : 0.0f;
        float b1v_ = (ib < 28) ? Bp[28 + ib] : 0.0f;
        a = fmaf(dW2[k],      b0v_, a);
        a = fmaf(dW2[15 + k], b1v_, a);
      }
      orow[8171 + tid] = a;
    }
  }
}

extern "C" void kernel_launch(void* const* d_in, const int* in_sizes, int n_in,
                              void* d_out, int out_size, void* d_ws, size_t ws_size,
                              hipStream_t stream) {
  const float* x   = (const float*)d_in[0];
  const float* W1  = (const float*)d_in[1];
  const float* b1  = (const float*)d_in[2];
  const float* W2  = (const float*)d_in[3];
  const float* b2  = (const float*)d_in[4];
  const float* fcW = (const float*)d_in[5];
  const float* fcb = (const float*)d_in[6];
  const float* dW0 = (const float*)d_in[7];
  const float* db0 = (const float*)d_in[8];
  const float* dW1 = (const float*)d_in[9];
  const float* db1 = (const float*)d_in[10];
  const float* dW2 = (const float*)d_in[11];
  const float* db2 = (const float*)d_in[12];

  float* o        = (float*)d_out;
  float* out_main = o + OFF_OUT;
  float* latent   = o + OFF_LAT;
  float* sig      = o + OFF_SIG;
  float* pP  = o + OFF_P;
  float* pF  = o + OFF_F;
  float* pA  = o + OFF_A;
  float* pB0 = o + OFF_B0;

  const size_t lds_fused = L_TOT * sizeof(float);   // 34296 B -> 4 blocks/CU
  conv_fft_kernel<<<dim3(EE, BB), 512, lds_fused, stream>>>(
      x, W1, b1, W2, b2, fcW, fcb, latent, pP, pF, pA, pB0);
  sig_deconv_kernel<<<dim3(TT/TILE_C, BB), 256, 0, stream>>>(
      pP, pF, pA, pB0, dW0, db0, dW1, db1, dW2, db2, sig, out_main);
}

// Round 9
// 308.078 us; speedup vs baseline: 1.0766x; 1.0766x over previous
//
#include <hip/hip_runtime.h>
#include <math.h>

#define TT 8192
#define BB 256
#define EE 8
#define KK 15
#define PI_F  3.14159265358979323846f
#define TPI_F 6.28318530717958647692f

// d_out flat layout (reference tuple order)
#define OFF_OUT 0
#define OFF_LAT (BB*TT)
#define OFF_SIG (OFF_LAT + BB*EE*TT)
#define OFF_P   (OFF_SIG + BB*EE*TT)
#define OFF_F   (OFF_P + BB*EE)
#define OFF_A   (OFF_F + BB*EE)
#define OFF_B0  (OFF_A + BB*EE)

// swizzle for fft LDS only
#define SWZ(i) ((i) + ((i) >> 5))
#define NF 4096

// fused-kernel LDS layout (floats). re/im: SWZ(4095)+1 = 4223 each.
// R9 hybrid: sxp staged ONLY for e in [1,3] (max 4336 floats, e=3).
// e=0 reads contiguous float2 windows direct; e>=4 reads strided direct
// (lanes span ph -> segments >= 64B). LDS 12910 fl = 51640 B -> 3 blk/CU.
#define L_RE   0
#define L_IM   4223
#define L_SW   8446        // 96 floats
#define L_RBUF 8542        // 32 floats
#define L_SXP  8574        // 4336 floats (e=3 worst: 8*542)
#define L_TOT  12910

__device__ __forceinline__ float rdfl(float v) {
  return __uint_as_float(__builtin_amdgcn_readfirstlane(__float_as_uint(v)));
}

__device__ __forceinline__ int rev4(int k) {   // base-4 digit reversal, 6 digits
  unsigned r = __brev((unsigned)k) >> 20;      // 12-bit bit reversal
  return (int)(((r & 0x555u) << 1) | ((r >> 1) & 0x555u));
}

// =====================================================================
// FUSED Kernel A+B: composed dilated conv -> real-packed FFT -> moments
// + fc phase, one block per (e, b). 2048 blocks x 512 threads.
//
// R9: per-e conv load path (R8 post-mortem: staging only needed where
// direct global reads are uncoalesced):
//   e == 0      : per-thread CONTIGUOUS window -> 16x float2 loads.
//   e in [1,3]  : R7's verified half-row polyphase LDS staging
//                 (d=2..8 direct would be 8-32B segments -> VMEM storm).
//   e >= 4      : R8's verified direct strided loads (segments >= 64B).
// LDS 51.6 KB -> 3 blocks/CU (was 2 at 66 KB); phase-diverse blocks
// (conv/fc/fft/moments) overlap across the CU's pipes.
// =====================================================================
__global__ __launch_bounds__(512) void conv_fft_kernel(
    const float* __restrict__ x, const float* __restrict__ W1,
    const float* __restrict__ b1, const float* __restrict__ W2,
    const float* __restrict__ b2, const float* __restrict__ fcW,
    const float* __restrict__ fcb, float* __restrict__ latent,
    float* __restrict__ outP, float* __restrict__ outF,
    float* __restrict__ outA, float* __restrict__ outB0)
{
  extern __shared__ float smem[];
  float* re   = smem + L_RE;
  float* im   = smem + L_IM;
  float* sW   = smem + L_SW;
  float* rbuf = smem + L_RBUF;
  float* sxp  = smem + L_SXP;

  const int e = blockIdx.x, b = blockIdx.y;
  const int d  = 1 << e;
  const int M  = TT >> e;                   // outputs per phase (full row)
  const int tid = threadIdx.x;
  const float* xr = x + b * TT;

  // ---- weights: composed 29-tap + raw
  if (tid < 29) {
    float acc = 0.0f;
    for (int c = 0; c < 2; c++) {
      const float* w1 = W1 + e*30 + c*15;
      const float* w2 = W2 + e*30 + c*15;
      int jlo = tid - 14; if (jlo < 0) jlo = 0;
      int jhi = tid;      if (jhi > 14) jhi = 14;
      for (int j = jlo; j <= jhi; j++) acc += w2[j] * w1[tid - j];
    }
    sW[tid] = acc;
  } else if (tid == 29) {
    float s20 = 0.f, s21 = 0.f;
    for (int j = 0; j < 15; j++) { s20 += W2[e*30 + j]; s21 += W2[e*30 + 15 + j]; }
    sW[29] = b2[e] + s20*b1[e*2] + s21*b1[e*2 + 1];
  } else if (tid >= 32 && tid < 62) {
    sW[tid] = W1[e*30 + (tid - 32)];
  } else if (tid >= 64 && tid < 94) {
    sW[tid] = W2[e*30 + (tid - 64)];
  } else if (tid == 94 || tid == 95) {
    sW[tid] = b1[e*2 + (tid - 94)];
  }
  __syncthreads();

  float Wc[29];
  #pragma unroll
  for (int s = 0; s < 29; s++) Wc[s] = rdfl(sW[s]);
  const float Bc = rdfl(sW[29]);

  if (e >= 1 && e <= 3) {
    // ============ STAGED PATH (R7 verified, half-row h-loop) ============
    const int Mh = (TT/2) >> e;
    const int Lp = ((((Mh - 2) + 31) >> 5) << 5) + 30;   // >= Mh+28, ==30 mod 32

    #pragma unroll 1
    for (int h = 0; h < 2; ++h) {
      const int tbase = h * (TT/2) - 14 * d;
      const int nstage = (TT/2) + 28 * d;
      for (int i = tid; i < nstage; i += 512) {
        int t  = tbase + i;
        int ph = i & (d - 1);
        int n  = i >> e;
        sxp[ph * Lp + n] = (t >= 0 && t < TT) ? xr[t] : 0.0f;
      }
      __syncthreads();

      float* lrh = latent + (b * EE + e) * TT + h * (TT/2);

      #pragma unroll 1
      for (int g = 0; g < 2; g++) {
        const int vt = g * 512 + tid;
        const int ph = vt & (d - 1);
        const int m0 = (vt >> e) << 2;

        float win[32];
        {
          const float2* wp = (const float2*)&sxp[ph * Lp + m0];
          #pragma unroll
          for (int v = 0; v < 16; v++) {
            float2 qv = wp[v];
            win[2*v] = qv.x; win[2*v+1] = qv.y;
          }
        }
        float acc[4] = {Bc, Bc, Bc, Bc};
        #pragma unroll
        for (int s = 0; s < 29; s++) {
          #pragma unroll
          for (int r = 0; r < 4; r++) acc[r] = fmaf(Wc[s], win[s + r], acc[r]);
        }

        if (h == 0 && g == 0 && m0 <= 6) {
          #pragma unroll
          for (int r = 0; r < 4; r++) {
            float corr = 0.0f;
            #pragma unroll
            for (int j = 0; j < 7; j++) {
              if (m0 + r + j <= 6) {
                float a0 = sW[94], a1 = sW[95];
                #pragma unroll
                for (int k = 0; k < 15; k++) {
                  float xv = win[r + j + k];
                  a0 = fmaf(sW[32 + k], xv, a0);
                  a1 = fmaf(sW[47 + k], xv, a1);
                }
                corr = fmaf(sW[64 + j], a0, corr);
                corr = fmaf(sW[79 + j], a1, corr);
              }
            }
            acc[r] -= corr;
          }
        }
        if (h == 1 && g == 1 && m0 + 3 >= Mh - 7) {
          #pragma unroll
          for (int r = 0; r < 4; r++) {
            float corr = 0.0f;
            #pragma unroll
            for (int jj = 0; jj < 7; jj++) {
              const int j = 8 + jj;
              if (m0 + r + j >= Mh + 7) {
                float a0 = sW[94], a1 = sW[95];
                #pragma unroll
                for (int k = 0; k < 15; k++) {
                  float xv = win[r + j + k];
                  a0 = fmaf(sW[32 + k], xv, a0);
                  a1 = fmaf(sW[47 + k], xv, a1);
                }
                corr = fmaf(sW[64 + j], a0, corr);
                corr = fmaf(sW[79 + j], a1, corr);
              }
            }
            acc[r] -= corr;
          }
        }

        #pragma unroll
        for (int r = 0; r < 4; r++) {
          int toff = ph + (m0 + r) * d;
          lrh[toff] = acc[r];
          int tg = h * (TT/2) + toff;
          int n  = tg >> 1;
          float* dst = (tg & 1) ? im : re;
          dst[SWZ(n)] = acc[r];
        }
      }
      __syncthreads();   // sxp safe to overwrite; last iter: scatter visible
    }
  } else {
    // ============ DIRECT PATH (e==0 contiguous, e>=4 strided) ============
    float* lr = latent + (b * EE + e) * TT;

    #pragma unroll 1
    for (int g = 0; g < 4; g++) {
      const int vt = g * 512 + tid;            // 0..2047
      const int ph = vt & (d - 1);
      const int m0 = (vt >> e) << 2;
      const int nbase = m0 - 14;

      float win[32];
      if (e == 0) {
        if (m0 >= 16 && m0 <= M - 20) {
          const float2* xq2 = (const float2*)(xr + nbase);  // nbase even
          #pragma unroll
          for (int v = 0; v < 16; v++) {
            float2 qv = xq2[v];
            win[2*v] = qv.x; win[2*v+1] = qv.y;
          }
        } else {
          #pragma unroll
          for (int s = 0; s < 32; s++) {
            int ns = nbase + s;
            win[s] = ((unsigned)ns < (unsigned)M) ? xr[ns] : 0.0f;
          }
        }
      } else {
        const float* xp = xr + ph;
        if (m0 >= 16 && m0 <= M - 20) {
          #pragma unroll
          for (int s = 0; s < 32; s++) win[s] = xp[(nbase + s) * d];
        } else {
          #pragma unroll
          for (int s = 0; s < 32; s++) {
            int ns = nbase + s;
            win[s] = ((unsigned)ns < (unsigned)M) ? xp[ns * d] : 0.0f;
          }
        }
      }

      float acc[4] = {Bc, Bc, Bc, Bc};
      #pragma unroll
      for (int s = 0; s < 29; s++) {
        #pragma unroll
        for (int r = 0; r < 4; r++) acc[r] = fmaf(Wc[s], win[s + r], acc[r]);
      }

      if (m0 <= 6) {
        #pragma unroll
        for (int r = 0; r < 4; r++) {
          float corr = 0.0f;
          #pragma unroll
          for (int j = 0; j < 7; j++) {
            if (m0 + r + j <= 6) {
              float a0 = sW[94], a1 = sW[95];
              #pragma unroll
              for (int k = 0; k < 15; k++) {
                float xv = win[r + j + k];
                a0 = fmaf(sW[32 + k], xv, a0);
                a1 = fmaf(sW[47 + k], xv, a1);
              }
              corr = fmaf(sW[64 + j], a0, corr);
              corr = fmaf(sW[79 + j], a1, corr);
            }
          }
          acc[r] -= corr;
        }
      }
      if (m0 + 3 >= M - 7) {
        #pragma unroll
        for (int r = 0; r < 4; r++) {
          float corr = 0.0f;
          #pragma unroll
          for (int jj = 0; jj < 7; jj++) {
            const int j = 8 + jj;
            if (m0 + r + j >= M + 7) {
              float a0 = sW[94], a1 = sW[95];
              #pragma unroll
              for (int k = 0; k < 15; k++) {
                float xv = win[r + j + k];
                a0 = fmaf(sW[32 + k], xv, a0);
                a1 = fmaf(sW[47 + k], xv, a1);
              }
              corr = fmaf(sW[64 + j], a0, corr);
              corr = fmaf(sW[79 + j], a1, corr);
            }
          }
          acc[r] -= corr;
        }
      }

      #pragma unroll
      for (int r = 0; r < 4; r++) {
        int tg = ph + (m0 + r) * d;
        lr[tg] = acc[r];
        int n  = tg >> 1;
        float* dst = (tg & 1) ? im : re;
        dst[SWZ(n)] = acc[r];
      }
    }
    __syncthreads();
  }

  // ---- fc dot-product pass
  const float2* f02 = (const float2*)(fcW + (e*2 + 0)*TT);
  const float2* f12 = (const float2*)(fcW + (e*2 + 1)*TT);
  float v0 = 0.f, v1 = 0.f;
  for (int n = tid; n < NF; n += 512) {
    float zr = re[SWZ(n)], zi = im[SWZ(n)];
    float2 a0 = f02[n], a1 = f12[n];
    v0 = fmaf(zr, a0.x, v0); v0 = fmaf(zi, a0.y, v0);
    v1 = fmaf(zr, a1.x, v1); v1 = fmaf(zi, a1.y, v1);
  }
  __syncthreads();

  // ---- radix-4 DIF stages
  for (int L = NF >> 2; L >= 1; L >>= 2) {
    float wstep = -1.57079632679f / (float)L;
    for (int u = tid; u < (NF >> 2); u += 512) {
      int p = u & (L - 1);
      int base = ((u - p) << 2) + p;
      int i0 = SWZ(base), i1 = SWZ(base + L), i2 = SWZ(base + 2*L), i3 = SWZ(base + 3*L);
      float ar = re[i0], ai = im[i0];
      float br = re[i1], bi = im[i1];
      float cr = re[i2], ci = im[i2];
      float dr = re[i3], di = im[i3];
      float t0r = ar + cr, t0i = ai + ci;
      float t1r = ar - cr, t1i = ai - ci;
      float t2r = br + dr, t2i = bi + di;
      float t3r = br - dr, t3i = bi - di;
      float A0r = t0r + t2r, A0i = t0i + t2i;
      float A1r = t1r + t3i, A1i = t1i - t3r;
      float A2r = t0r - t2r, A2i = t0i - t2i;
      float A3r = t1r - t3i, A3i = t1i + t3r;
      float ang = wstep * (float)p;
      float s1 = __sinf(ang), c1 = __cosf(ang);
      float c2 = c1*c1 - s1*s1, s2 = 2.f*c1*s1;
      float c3 = c1*c2 - s1*s2, s3 = c1*s2 + s1*c2;
      re[i0] = A0r;                 im[i0] = A0i;
      re[i1] = A1r*c1 - A1i*s1;     im[i1] = A1r*s1 + A1i*c1;
      re[i2] = A2r*c2 - A2i*s2;     im[i2] = A2r*s2 + A2i*c2;
      re[i3] = A3r*c3 - A3i*s3;     im[i3] = A3r*s3 + A3i*c3;
    }
    __syncthreads();
  }

  // ---- moments over unpacked real spectrum
  float pacc = 0.f, facc = 0.f;
  for (int k = 1 + tid; k < NF; k += 512) {
    int jk = SWZ(rev4(k));
    int jm = SWZ(rev4(NF - k));
    float zr = re[jk], zi = im[jk];
    float yr = re[jm], yi = im[jm];
    float Er = 0.5f*(zr + yr), Ei = 0.5f*(zi - yi);
    float Dr = 0.5f*(zr - yr), Di = 0.5f*(zi + yi);
    float Or = Di, Oi = -Dr;
    float ang = -PI_F * (float)k / (float)NF;
    float s = __sinf(ang), c = __cosf(ang);
    float Xr = Er + c*Or - s*Oi;
    float Xi = Ei + c*Oi + s*Or;
    float mag = fmaf(Xr, Xr, Xi*Xi);
    pacc += mag;
    facc = fmaf(0.5f * (float)k, mag, facc);
  }
  if (tid == 0) {
    float X = re[SWZ(0)] - im[SWZ(0)];
    pacc += X*X;
    facc += 2048.0f * X*X;
  }

  #pragma unroll
  for (int off = 32; off > 0; off >>= 1) {
    pacc += __shfl_down(pacc, off);
    facc += __shfl_down(facc, off);
    v0   += __shfl_down(v0, off);
    v1   += __shfl_down(v1, off);
  }
  int wid = tid >> 6, lane = tid & 63;
  if (lane == 0) {
    rbuf[wid*4 + 0] = pacc; rbuf[wid*4 + 1] = facc;
    rbuf[wid*4 + 2] = v0;   rbuf[wid*4 + 3] = v1;
  }
  __syncthreads();
  if (tid == 0) {
    float P = 0.f, Fw = 0.f, V0 = 0.f, V1 = 0.f;
    #pragma unroll
    for (int w = 0; w < 8; w++) {
      P += rbuf[w*4]; Fw += rbuf[w*4+1]; V0 += rbuf[w*4+2]; V1 += rbuf[w*4+3];
    }
    float z0r = re[SWZ(0)], z0i = im[SWZ(0)];
    float amp  = 2.0f * sqrtf(P) / (float)TT;
    float boff = (z0r + z0i) / (float)TT;
    float vv0 = V0 + fcb[e*2 + 0];
    float vv1 = V1 + fcb[e*2 + 1];
    float ph  = atan2f(vv1, vv0) / TPI_F;
    int idx = b*EE + e;
    outP[idx]  = ph;
    outF[idx]  = Fw / P;
    outA[idx]  = amp;
    outB0[idx] = boff;
  }
}

// =====================================================================
// Kernel C: sinusoid reconstruction + deconv tree, FULLY CLOSED-FORM.
// (UNCHANGED from R7 -- passed, ~write-bound floor.)
// =====================================================================
#define TILE_C 512
// patch LDS offsets (floats)
#define P_S   128           // 8 x 42
#define P_A   472           // 4 x 35
#define P_B   616           // 2 x 28
#define P_TOT 704

__global__ __launch_bounds__(256) void sig_deconv_kernel(
    const float* __restrict__ Pv, const float* __restrict__ Fv,
    const float* __restrict__ Av, const float* __restrict__ B0v,
    const float* __restrict__ dW0, const float* __restrict__ db0,
    const float* __restrict__ dW1, const float* __restrict__ db1,
    const float* __restrict__ dW2, const float* __restrict__ db2,
    float* __restrict__ sig, float* __restrict__ out)
{
  __shared__ float smem[P_TOT];

  const int tile = blockIdx.x, b = blockIdx.y;
  const int t0 = tile * TILE_C;
  const int tid = threadIdx.x;
  const float step = 2.0f / 8191.0f;

  float fs[8], am[8], psh[8], bo[8];
  #pragma unroll
  for (int ch = 0; ch < EE; ch++) {
    int idx = b*EE + ch;
    fs[ch] = Fv[idx]; am[ch] = Av[idx]; psh[ch] = Pv[idx]; bo[ch] = B0v[idx];
  }

  float* hre   = smem;          // [lvl*8 + ch]
  float* him   = smem + 24;
  float* ssum  = smem + 48;
  float* Cs    = smem + 72;     // am*Re(Htot)
  float* Cc    = smem + 80;     // am*Im(Htot)
  float* chDC  = smem + 88;
  float* bDC   = smem + 96;

  if (tid < 24) {
    int ch  = tid & 7;
    int lvl = tid >> 3;
    const float* w;
    if (lvl == 0)      w = dW0 + (ch >> 1)*30 + (ch & 1)*15;
    else if (lvl == 1) w = dW1 + (ch >> 2)*30 + ((ch >> 1) & 1)*15;
    else               w = dW2 + (ch >> 2)*15;
    float om = TPI_F * fs[ch] * step;       // per-sample angular freq
    float ar = 0.f, ai = 0.f, sm = 0.f;
    #pragma unroll
    for (int k = 0; k < 15; k++) {
      float wk = w[k];
      float ang = (float)(k - 7) * om;
      ar = fmaf(wk, __cosf(ang), ar);
      ai = fmaf(wk, __sinf(ang), ai);
      sm += wk;
    }
    hre[tid] = ar; him[tid] = ai; ssum[tid] = sm;
  }
  __syncthreads();

  if (tid < 8) {
    int ch = tid;
    float r0 = hre[ch],      i0 = him[ch];
    float r1 = hre[8 + ch],  i1 = him[8 + ch];
    float r2 = hre[16 + ch], i2 = him[16 + ch];
    float ra = r0*r1 - i0*i1, ia = r0*i1 + i0*r1;
    float rt = ra*r2 - ia*i2, it = ra*i2 + ia*r2;
    Cs[ch] = am[ch] * rt;
    Cc[ch] = am[ch] * it;
    chDC[ch] = bo[ch] * ssum[ch] * ssum[8 + ch] * ssum[16 + ch];
  } else if (tid == 8) {
    float acc = db2[0];
    #pragma unroll
    for (int g0 = 0; g0 < 4; g0++)
      acc = fmaf(db0[g0], ssum[8 + 2*g0] * ssum[16 + 2*g0], acc);
    #pragma unroll
    for (int g1 = 0; g1 < 2; g1++)
      acc = fmaf(db1[g1], ssum[16 + 4*g1], acc);
    bDC[0] = acc;
  }
  __syncthreads();

  float cs[8], cc[8];
  float DC = bDC[0];
  #pragma unroll
  for (int ch = 0; ch < 8; ch++) {
    cs[ch] = Cs[ch]; cc[ch] = Cc[ch]; DC += chDC[ch];
  }

  const int tmin = (tile == 0)  ? 21        : 0;
  const int tmax = (tile == 15) ? (TT - 21) : TT;
  float* orow = out + b*TT;
  #pragma unroll
  for (int it = 0; it < 2; ++it) {
    int t = t0 + it*256 + tid;
    float arg = fmaf(step, (float)t, -1.0f);
    float o = DC;
    #pragma unroll
    for (int ch = 0; ch < 8; ch++) {
      float rr = fmaf(fs[ch], arg, psh[ch]);
      rr -= rintf(rr);
      float th = TPI_F * rr;
      float s = __sinf(th);
      float c = __cosf(th);
      sig[(b*EE + ch)*TT + t] = fmaf(am[ch], s, bo[ch]);
      o = fmaf(s, cs[ch], o);
      o = fmaf(c, cc[ch], o);
    }
    if (t >= tmin && t < tmax) orow[t] = o;
  }

  // ---- exact border patches (clipped support); head in tile 0, tail in 15
  if (tile == 0) {
    float* Sp = smem + P_S;   // [ch*42 + j], t = j
    float* Ap = smem + P_A;   // [g*35 + j],  v = j
    float* Bp = smem + P_B;   // [g1*28 + j], u = j
    __syncthreads();
    for (int idx = tid; idx < 336; idx += 256) {
      int ch = idx / 42, j = idx - ch*42;
      float arg = fmaf(step, (float)j, -1.0f);
      float rr = fmaf(fs[ch], arg, psh[ch]);
      rr -= rintf(rr);
      Sp[idx] = fmaf(am[ch], __sinf(TPI_F * rr), bo[ch]);
    }
    __syncthreads();
    if (tid < 140) {
      int g = tid / 35, j = tid - g*35;
      float a = db0[g];
      #pragma unroll
      for (int k = 0; k < 15; k++) {
        int is = j + k - 7;
        float s0 = (is >= 0) ? Sp[(2*g)*42 + is]     : 0.0f;
        float s1 = (is >= 0) ? Sp[(2*g+1)*42 + is]   : 0.0f;
        a = fmaf(dW0[g*30 + k],      s0, a);
        a = fmaf(dW0[g*30 + 15 + k], s1, a);
      }
      Ap[tid] = a;
    }
    __syncthreads();
    if (tid < 56) {
      int g1 = tid / 28, j = tid - g1*28;
      float a = db1[g1];
      #pragma unroll
      for (int k = 0; k < 15; k++) {
        int ia = j + k - 7;
        float a0 = (ia >= 0) ? Ap[(2*g1)*35 + ia]   : 0.0f;
        float a1 = (ia >= 0) ? Ap[(2*g1+1)*35 + ia] : 0.0f;
        a = fmaf(dW1[g1*30 + k],      a0, a);
        a = fmaf(dW1[g1*30 + 15 + k], a1, a);
      }
      Bp[tid] = a;
    }
    __syncthreads();
    if (tid < 21) {
      float a = db2[0];
      #pragma unroll
      for (int k = 0; k < 15; k++) {
        int ib = tid + k - 7;
        float b0v_ = (ib >= 0) ? Bp[ib]      : 0.0f;
        float b1v_ = (ib >= 0) ? Bp[28 + ib] : 0.0f;
        a = fmaf(dW2[k],      b0v_, a);
        a = fmaf(dW2[15 + k], b1v_, a);
      }
      orow[tid] = a;
    }
  }
  if (tile == 15) {
    float* Sp = smem + P_S;   // [ch*42 + j], t = 8150 + j
    float* Ap = smem + P_A;   // [g*35 + j],  v = 8157 + j
    float* Bp = smem + P_B;   // [g1*28 + j], u = 8164 + j
    __syncthreads();
    for (int idx = tid; idx < 336; idx += 256) {
      int ch = idx / 42, j = idx - ch*42;
      int t = 8150 + j;
      float arg = fmaf(step, (float)t, -1.0f);
      float rr = fmaf(fs[ch], arg, psh[ch]);
      rr -= rintf(rr);
      Sp[idx] = fmaf(am[ch], __sinf(TPI_F * rr), bo[ch]);
    }
    __syncthreads();
    if (tid < 140) {
      int g = tid / 35, j = tid - g*35;
      float a = db0[g];
      #pragma unroll
      for (int k = 0; k < 15; k++) {
        int is = j + k;                     // local S idx; global = v+k-7
        float s0 = (is < 42) ? Sp[(2*g)*42 + is]   : 0.0f;
        float s1 = (is < 42) ? Sp[(2*g+1)*42 + is] : 0.0f;
        a = fmaf(dW0[g*30 + k],      s0, a);
        a = fmaf(dW0[g*30 + 15 + k], s1, a);
      }
      Ap[tid] = a;
    }
    __syncthreads();
    if (tid < 56) {
      int g1 = tid / 28, j = tid - g1*28;
      float a = db1[g1];
      #pragma unroll
      for (int k = 0; k < 15; k++) {
        int ia = j + k;
        float a0 = (ia < 35) ? Ap[(2*g1)*35 + ia]   : 0.0f;
        float a1 = (ia < 35) ? Ap[(2*g1+1)*35 + ia] : 0.0f;
        a = fmaf(dW1[g1*30 + k],      a0, a);
        a = fmaf(dW1[g1*30 + 15 + k], a1, a);
      }
      Bp[tid] = a;
    }
    __syncthreads();
    if (tid < 21) {
      float a = db2[0];
      #pragma unroll
      for (int k = 0; k < 15; k++) {
        int ib = tid + k;
        float b0v_ = (ib < 28) ? Bp[ib]      : 0.0f;
        float b1v_ = (ib < 28) ? Bp[28 + ib] : 0.0f;
        a = fmaf(dW2[k],      b0v_, a);
        a = fmaf(dW2[15 + k], b1v_, a);
      }
      orow[8171 + tid] = a;
    }
  }
}

extern "C" void kernel_launch(void* const* d_in, const int* in_sizes, int n_in,
                              void* d_out, int out_size, void* d_ws, size_t ws_size,
                              hipStream_t stream) {
  const float* x   = (const float*)d_in[0];
  const float* W1  = (const float*)d_in[1];
  const float* b1  = (const float*)d_in[2];
  const float* W2  = (const float*)d_in[3];
  const float* b2  = (const float*)d_in[4];
  const float* fcW = (const float*)d_in[5];
  const float* fcb = (const float*)d_in[6];
  const float* dW0 = (const float*)d_in[7];
  const float* db0 = (const float*)d_in[8];
  const float* dW1 = (const float*)d_in[9];
  const float* db1 = (const float*)d_in[10];
  const float* dW2 = (const float*)d_in[11];
  const float* db2 = (const float*)d_in[12];

  float* o        = (float*)d_out;
  float* out_main = o + OFF_OUT;
  float* latent   = o + OFF_LAT;
  float* sig      = o + OFF_SIG;
  float* pP  = o + OFF_P;
  float* pF  = o + OFF_F;
  float* pA  = o + OFF_A;
  float* pB0 = o + OFF_B0;

  const size_t lds_fused = L_TOT * sizeof(float);   // 51640 B -> 3 blocks/CU
  conv_fft_kernel<<<dim3(EE, BB), 512, lds_fused, stream>>>(
      x, W1, b1, W2, b2, fcW, fcb, latent, pP, pF, pA, pB0);
  sig_deconv_kernel<<<dim3(TT/TILE_C, BB), 256, 0, stream>>>(
      pP, pF, pA, pB0, dW0, db0, dW1, db1, dW2, db2, sig, out_main);
}